// Round 3
// baseline (1042.888 us; speedup 1.0000x reference)
//
#include <hip/hip_runtime.h>

#define NN 100000
#define NE 1600000
#define DF 32
#define DEPTH 10
#define LSTRIDE ((DEPTH + 1) * DF) /* 352 floats per node in d_out */
#define SCAN_BLOCKS 256
#define SCAN_T 256
#define RPB 128           /* rows per bucket */
#define BCAP 2560         /* max edges per bucket (mean 2048, +11 sigma) */

__global__ void hist_k(const int* __restrict__ row, int* __restrict__ cnt, int e) {
    int i = blockIdx.x * blockDim.x + threadIdx.x;
    int stride = gridDim.x * blockDim.x;
    for (; i < e; i += stride) atomicAdd(&cnt[row[i]], 1);
}

__global__ void dinv_k(const int* __restrict__ cnt, float* __restrict__ dinv, int n) {
    int i = blockIdx.x * blockDim.x + threadIdx.x;
    if (i < n) {
        int c = cnt[i];
        float d = (c == 0) ? 1.0f : (float)c;
        dinv[i] = rsqrtf(d);
    }
}

// --- multi-block scan: partial sums -> scan block sums -> emit ---
__global__ void scan_partial_k(const int* __restrict__ cnt, int* __restrict__ bsum,
                               int n, int chunk) {
    __shared__ int red[SCAN_T];
    int b = blockIdx.x, t = threadIdx.x;
    int beg = b * chunk, end = min(n, beg + chunk);
    int s = 0;
    for (int i = beg + t; i < end; i += SCAN_T) s += cnt[i];
    red[t] = s;
    __syncthreads();
    for (int off = SCAN_T / 2; off; off >>= 1) {
        if (t < off) red[t] += red[t + off];
        __syncthreads();
    }
    if (t == 0) bsum[b] = red[0];
}

__global__ void scan_bsum_k(const int* __restrict__ bsum, int* __restrict__ boff) {
    __shared__ int s[SCAN_BLOCKS];
    int t = threadIdx.x;
    s[t] = bsum[t];
    __syncthreads();
    for (int off = 1; off < SCAN_BLOCKS; off <<= 1) {
        int v = (t >= off) ? s[t - off] : 0;
        __syncthreads();
        s[t] += v;
        __syncthreads();
    }
    boff[t] = (t == 0) ? 0 : s[t - 1];
}

__global__ void scan_emit_k(const int* __restrict__ cnt, const int* __restrict__ boff,
                            int* __restrict__ rowptr, int n, int chunk) {
    __shared__ int tile[SCAN_T];
    int b = blockIdx.x, t = threadIdx.x;
    int beg = b * chunk, end = min(n, beg + chunk);
    int run = boff[b];
    for (int base = beg; base < end; base += SCAN_T) {
        int i = base + t;
        int c = (i < end) ? cnt[i] : 0;
        tile[t] = c;
        __syncthreads();
        for (int off = 1; off < SCAN_T; off <<= 1) {
            int v = (t >= off) ? tile[t - off] : 0;
            __syncthreads();
            tile[t] += v;
            __syncthreads();
        }
        if (i < end) rowptr[i] = run + tile[t] - c; // exclusive prefix
        run += tile[SCAN_T - 1];
        __syncthreads();
    }
    if (b == gridDim.x - 1 && t == 0) rowptr[n] = run;
}

// Phase A: append edges into row-buckets. Packed entry: ((row&127)<<17)|col, val.
// Appends keep only ~nbuck hot tail-lines live -> near-dense writes.
__global__ void binA_k(const int* __restrict__ row, const int* __restrict__ col,
                       const float* __restrict__ ea, const float* __restrict__ dinv,
                       int* __restrict__ bfill, int2* __restrict__ stage, int e) {
    int i = blockIdx.x * blockDim.x + threadIdx.x;
    int stride = gridDim.x * blockDim.x;
    for (; i < e; i += stride) {
        int r = row[i], c = col[i];
        float v = dinv[r] * ea[i] * dinv[c];
        int b = r >> 7;
        int pos = atomicAdd(&bfill[b], 1);
        stage[(size_t)b * BCAP + pos] =
            make_int2((int)(((unsigned)(r & (RPB - 1)) << 17) | (unsigned)c), __float_as_int(v));
    }
}

// Phase B: per-bucket LDS counting-sort into final CSR order; coalesced emit.
__global__ __launch_bounds__(256) void binB_k(const int2* __restrict__ stage,
                                              const int* __restrict__ bfill,
                                              const int* __restrict__ rowptr,
                                              int2* __restrict__ cpack, int n) {
    __shared__ int2 srt[BCAP];
    __shared__ int lfill[RPB];
    int b = blockIdx.x, t = threadIdx.x;
    int r0 = b * RPB;
    int rcount = min(RPB, n - r0);
    for (int i = t; i < rcount; i += 256) lfill[i] = 0;
    __syncthreads();
    int m = bfill[b];
    int g0 = rowptr[r0];
    const int2* sb = stage + (size_t)b * BCAP;
    for (int i = t; i < m; i += 256) {
        int2 e = sb[i];
        int rl = ((unsigned)e.x) >> 17;
        int pos = rowptr[r0 + rl] - g0 + atomicAdd(&lfill[rl], 1);
        srt[pos] = make_int2(e.x & 0x1FFFF, e.y);
    }
    __syncthreads();
    for (int i = t; i < m; i += 256) cpack[g0 + i] = srt[i];
}

// out[node][0][:] = x[node][:]  (float4 vectorized)
__global__ void copy_k(const float* __restrict__ x, float* __restrict__ out, int n) {
    int t = blockIdx.x * blockDim.x + threadIdx.x; // n*8 float4s
    if (t < n * 8) {
        int node = t >> 3, q = t & 7;
        ((float4*)out)[(size_t)node * (LSTRIDE / 4) + q] = ((const float4*)x)[t];
    }
}

// one 32-lane group per row; lane = feature; unroll-8; NT loads on streamed cpack,
// NT stores on output (no reuse within pass) to preserve L2 for h-gathers.
__global__ __launch_bounds__(256) void spmm_k(const int* __restrict__ rowptr,
                                              const unsigned long long* __restrict__ cpack,
                                              const float* __restrict__ pe,
                                              float* __restrict__ out, int n, int layer) {
    int gid = blockIdx.x * 8 + (threadIdx.x >> 5);
    int lane = threadIdx.x & 31;
    if (gid >= n) return;
    float alpha = tanhf(pe[layer]); // BASE_ALPHA = 1
    const float* __restrict__ hsrc = out + (size_t)layer * DF + lane;
    int beg = rowptr[gid], end = rowptr[gid + 1];
    float acc = 0.f;
    int e = beg;
    for (; e + 8 <= end; e += 8) {
        unsigned long long p[8];
#pragma unroll
        for (int u = 0; u < 8; ++u) p[u] = __builtin_nontemporal_load(&cpack[e + u]);
        float h[8];
#pragma unroll
        for (int u = 0; u < 8; ++u)
            h[u] = hsrc[(size_t)(unsigned)(p[u] & 0xFFFFFFFFu) * LSTRIDE];
#pragma unroll
        for (int u = 0; u < 8; ++u)
            acc = fmaf(__uint_as_float((unsigned)(p[u] >> 32)), h[u], acc);
    }
    for (; e < end; ++e) {
        unsigned long long p = __builtin_nontemporal_load(&cpack[e]);
        acc = fmaf(__uint_as_float((unsigned)(p >> 32)),
                   hsrc[(size_t)(unsigned)(p & 0xFFFFFFFFu) * LSTRIDE], acc);
    }
    __builtin_nontemporal_store(alpha * acc,
                                &out[(size_t)gid * LSTRIDE + (layer + 1) * DF + lane]);
}

extern "C" void kernel_launch(void* const* d_in, const int* in_sizes, int n_in,
                              void* d_out, int out_size, void* d_ws, size_t ws_size,
                              hipStream_t stream) {
    const float* x  = (const float*)d_in[0];
    const int*   ei = (const int*)d_in[1];
    const float* ea = (const float*)d_in[2];
    const float* pe = (const float*)d_in[3];
    float* out = (float*)d_out;

    const int n = in_sizes[0] / DF;   // 100000
    const int e = in_sizes[2];        // 1600000
    const int* row = ei;
    const int* col = ei + e;
    const int nbuck = (n + RPB - 1) / RPB; // 782

    // workspace layout
    int*   cnt    = (int*)d_ws;               // n
    int*   bfill  = cnt + n;                  // nbuck (contiguous w/ cnt for one memset)
    int*   rowptr = bfill + nbuck;            // n+1
    float* dinv   = (float*)(rowptr + n + 1); // n
    int*   bsum   = (int*)(dinv + n);         // SCAN_BLOCKS
    int*   boff   = bsum + SCAN_BLOCKS;       // SCAN_BLOCKS
    size_t off = ((size_t)(boff + SCAN_BLOCKS) - (size_t)d_ws + 15) & ~(size_t)15;
    int2*  stage = (int2*)((char*)d_ws + off);        // nbuck*BCAP int2 (~16MB)
    int2*  cpack = stage + (size_t)nbuck * BCAP;      // e int2 (~12.8MB)

    hipMemsetAsync(cnt, 0, (size_t)(n + nbuck) * sizeof(int), stream);

    const int chunk = (n + SCAN_BLOCKS - 1) / SCAN_BLOCKS;

    hist_k<<<2048, 256, 0, stream>>>(row, cnt, e);
    dinv_k<<<(n + 255) / 256, 256, 0, stream>>>(cnt, dinv, n);
    scan_partial_k<<<SCAN_BLOCKS, SCAN_T, 0, stream>>>(cnt, bsum, n, chunk);
    scan_bsum_k<<<1, SCAN_BLOCKS, 0, stream>>>(bsum, boff);
    scan_emit_k<<<SCAN_BLOCKS, SCAN_T, 0, stream>>>(cnt, boff, rowptr, n, chunk);
    binA_k<<<2048, 256, 0, stream>>>(row, col, ea, dinv, bfill, stage, e);
    binB_k<<<nbuck, 256, 0, stream>>>(stage, bfill, rowptr, cpack, n);
    copy_k<<<(n * 8 + 255) / 256, 256, 0, stream>>>(x, out, n);

    for (int L = 0; L < DEPTH; ++L) {
        spmm_k<<<(n + 7) / 8, 256, 0, stream>>>(rowptr, (const unsigned long long*)cpack,
                                                pe, out, n, L);
    }
}

// Round 4
// 674.717 us; speedup vs baseline: 1.5457x; 1.5457x over previous
//
#include <hip/hip_runtime.h>

#define NN 100000
#define NE 1600000
#define DF 32
#define DEPTH 10
#define LSTRIDE ((DEPTH + 1) * DF) /* 352 floats per node in d_out */
#define SCAN_BLOCKS 256
#define SCAN_T 256

// histogram + per-edge rank within its row (atomic result was free)
__global__ void hist_k(const int* __restrict__ row, int* __restrict__ cnt,
                       int* __restrict__ prank, int e) {
    int i = blockIdx.x * blockDim.x + threadIdx.x;
    int stride = gridDim.x * blockDim.x;
    for (; i < e; i += stride) {
        int r = __builtin_nontemporal_load(&row[i]);
        prank[i] = atomicAdd(&cnt[r], 1);
    }
}

__global__ void dinv_k(const int* __restrict__ cnt, float* __restrict__ dinv, int n) {
    int i = blockIdx.x * blockDim.x + threadIdx.x;
    if (i < n) {
        int c = cnt[i];
        float d = (c == 0) ? 1.0f : (float)c;
        dinv[i] = rsqrtf(d);
    }
}

// --- multi-block scan: partial sums -> scan block sums -> emit ---
__global__ void scan_partial_k(const int* __restrict__ cnt, int* __restrict__ bsum,
                               int n, int chunk) {
    __shared__ int red[SCAN_T];
    int b = blockIdx.x, t = threadIdx.x;
    int beg = b * chunk, end = min(n, beg + chunk);
    int s = 0;
    for (int i = beg + t; i < end; i += SCAN_T) s += cnt[i];
    red[t] = s;
    __syncthreads();
    for (int off = SCAN_T / 2; off; off >>= 1) {
        if (t < off) red[t] += red[t + off];
        __syncthreads();
    }
    if (t == 0) bsum[b] = red[0];
}

__global__ void scan_bsum_k(const int* __restrict__ bsum, int* __restrict__ boff) {
    __shared__ int s[SCAN_BLOCKS];
    int t = threadIdx.x;
    s[t] = bsum[t];
    __syncthreads();
    for (int off = 1; off < SCAN_BLOCKS; off <<= 1) {
        int v = (t >= off) ? s[t - off] : 0;
        __syncthreads();
        s[t] += v;
        __syncthreads();
    }
    boff[t] = (t == 0) ? 0 : s[t - 1];
}

__global__ void scan_emit_k(const int* __restrict__ cnt, const int* __restrict__ boff,
                            int* __restrict__ rowptr, int n, int chunk) {
    __shared__ int tile[SCAN_T];
    int b = blockIdx.x, t = threadIdx.x;
    int beg = b * chunk, end = min(n, beg + chunk);
    int run = boff[b];
    for (int base = beg; base < end; base += SCAN_T) {
        int i = base + t;
        int c = (i < end) ? cnt[i] : 0;
        tile[t] = c;
        __syncthreads();
        for (int off = 1; off < SCAN_T; off <<= 1) {
            int v = (t >= off) ? tile[t - off] : 0;
            __syncthreads();
            tile[t] += v;
            __syncthreads();
        }
        if (i < end) rowptr[i] = run + tile[t] - c; // exclusive prefix
        run += tile[SCAN_T - 1];
        __syncthreads();
    }
    if (b == gridDim.x - 1 && t == 0) rowptr[n] = run;
}

// atomic-free scatter: pos = rowptr[row] + prank
__global__ void scatter_k(const int* __restrict__ row, const int* __restrict__ col,
                          const float* __restrict__ ea, const float* __restrict__ dinv,
                          const int* __restrict__ rowptr, const int* __restrict__ prank,
                          int2* __restrict__ cpack, int e) {
    int i = blockIdx.x * blockDim.x + threadIdx.x;
    int stride = gridDim.x * blockDim.x;
    for (; i < e; i += stride) {
        int r = __builtin_nontemporal_load(&row[i]);
        int c = __builtin_nontemporal_load(&col[i]);
        float a = __builtin_nontemporal_load(&ea[i]);
        int pr = __builtin_nontemporal_load(&prank[i]);
        float v = dinv[r] * a * dinv[c];
        int pos = rowptr[r] + pr;
        cpack[pos] = make_int2(c, __float_as_int(v));
    }
}

// out[node][0][:] = x[node][:]  (float4 vectorized)
__global__ void copy_k(const float* __restrict__ x, float* __restrict__ out, int n) {
    int t = blockIdx.x * blockDim.x + threadIdx.x; // n*8 float4s
    if (t < n * 8) {
        int node = t >> 3, q = t & 7;
        ((float4*)out)[(size_t)node * (LSTRIDE / 4) + q] = ((const float4*)x)[t];
    }
}

// one 32-lane group per row; lane = feature; fully-masked unroll-8 (no serial tail).
__global__ __launch_bounds__(256) void spmm_k(const int* __restrict__ rowptr,
                                              const unsigned long long* __restrict__ cpack,
                                              const float* __restrict__ pe,
                                              float* __restrict__ out, int n, int layer) {
    int gid = blockIdx.x * 8 + (threadIdx.x >> 5);
    int lane = threadIdx.x & 31;
    if (gid >= n) return;
    float alpha = tanhf(pe[layer]); // BASE_ALPHA = 1
    const float* __restrict__ hsrc = out + (size_t)layer * DF + lane;
    int beg = rowptr[gid], end = rowptr[gid + 1];
    float acc = 0.f;
    for (int base = beg; base < end; base += 8) {
        unsigned long long p[8];
#pragma unroll
        for (int u = 0; u < 8; ++u) {
            int idx = base + u;
            p[u] = __builtin_nontemporal_load(&cpack[min(idx, end - 1)]);
        }
        float h[8];
#pragma unroll
        for (int u = 0; u < 8; ++u)
            h[u] = hsrc[(size_t)(unsigned)(p[u] & 0xFFFFFFFFu) * LSTRIDE];
#pragma unroll
        for (int u = 0; u < 8; ++u) {
            float v = (base + u < end) ? __uint_as_float((unsigned)(p[u] >> 32)) : 0.f;
            acc = fmaf(v, h[u], acc);
        }
    }
    out[(size_t)gid * LSTRIDE + (layer + 1) * DF + lane] = alpha * acc;
}

extern "C" void kernel_launch(void* const* d_in, const int* in_sizes, int n_in,
                              void* d_out, int out_size, void* d_ws, size_t ws_size,
                              hipStream_t stream) {
    const float* x  = (const float*)d_in[0];
    const int*   ei = (const int*)d_in[1];
    const float* ea = (const float*)d_in[2];
    const float* pe = (const float*)d_in[3];
    float* out = (float*)d_out;

    const int n = in_sizes[0] / DF;   // 100000
    const int e = in_sizes[2];        // 1600000
    const int* row = ei;
    const int* col = ei + e;

    // workspace layout
    int*   cnt    = (int*)d_ws;               // n
    int*   rowptr = cnt + n;                  // n+1
    float* dinv   = (float*)(rowptr + n + 1); // n
    int*   bsum   = (int*)(dinv + n);         // SCAN_BLOCKS
    int*   boff   = bsum + SCAN_BLOCKS;       // SCAN_BLOCKS
    int*   prank  = boff + SCAN_BLOCKS;       // e
    size_t off = ((size_t)(prank + e) - (size_t)d_ws + 15) & ~(size_t)15;
    int2*  cpack = (int2*)((char*)d_ws + off); // e int2s

    hipMemsetAsync(cnt, 0, (size_t)n * sizeof(int), stream);

    const int chunk = (n + SCAN_BLOCKS - 1) / SCAN_BLOCKS;

    hist_k<<<2048, 256, 0, stream>>>(row, cnt, prank, e);
    dinv_k<<<(n + 255) / 256, 256, 0, stream>>>(cnt, dinv, n);
    scan_partial_k<<<SCAN_BLOCKS, SCAN_T, 0, stream>>>(cnt, bsum, n, chunk);
    scan_bsum_k<<<1, SCAN_BLOCKS, 0, stream>>>(bsum, boff);
    scan_emit_k<<<SCAN_BLOCKS, SCAN_T, 0, stream>>>(cnt, boff, rowptr, n, chunk);
    scatter_k<<<2048, 256, 0, stream>>>(row, col, ea, dinv, rowptr, prank, cpack, e);
    copy_k<<<(n * 8 + 255) / 256, 256, 0, stream>>>(x, out, n);

    for (int L = 0; L < DEPTH; ++L) {
        spmm_k<<<(n + 7) / 8, 256, 0, stream>>>(rowptr, (const unsigned long long*)cpack,
                                                pe, out, n, L);
    }
}

// Round 5
// 539.170 us; speedup vs baseline: 1.9342x; 1.2514x over previous
//
#include <hip/hip_runtime.h>

#define NN 100000
#define NE 1600000
#define DF 32
#define DEPTH 10
#define LSTRIDE ((DEPTH + 1) * DF) /* 352 floats per node in d_out */
#define SCAN_BLOCKS 256
#define SCAN_T 256

// histogram + per-edge rank within its row (atomic result was free)
__global__ void hist_k(const int* __restrict__ row, int* __restrict__ cnt,
                       int* __restrict__ prank, int e) {
    int i = blockIdx.x * blockDim.x + threadIdx.x;
    int stride = gridDim.x * blockDim.x;
    for (; i < e; i += stride) {
        int r = __builtin_nontemporal_load(&row[i]);
        prank[i] = atomicAdd(&cnt[r], 1);
    }
}

// --- multi-block scan over PADDED counts ((cnt+7)&~7) ---
__global__ void scan_partial_k(const int* __restrict__ cnt, int* __restrict__ bsum,
                               int n, int chunk) {
    __shared__ int red[SCAN_T];
    int b = blockIdx.x, t = threadIdx.x;
    int beg = b * chunk, end = min(n, beg + chunk);
    int s = 0;
    for (int i = beg + t; i < end; i += SCAN_T) s += (cnt[i] + 7) & ~7;
    red[t] = s;
    __syncthreads();
    for (int off = SCAN_T / 2; off; off >>= 1) {
        if (t < off) red[t] += red[t + off];
        __syncthreads();
    }
    if (t == 0) bsum[b] = red[0];
}

__global__ void scan_bsum_k(const int* __restrict__ bsum, int* __restrict__ boff) {
    __shared__ int s[SCAN_BLOCKS];
    int t = threadIdx.x;
    s[t] = bsum[t];
    __syncthreads();
    for (int off = 1; off < SCAN_BLOCKS; off <<= 1) {
        int v = (t >= off) ? s[t - off] : 0;
        __syncthreads();
        s[t] += v;
        __syncthreads();
    }
    boff[t] = (t == 0) ? 0 : s[t - 1];
}

// emit padded-exclusive-prefix rowptr; also compute dinv from real cnt (fused).
__global__ void scan_emit_k(const int* __restrict__ cnt, const int* __restrict__ boff,
                            int* __restrict__ rowptr, float* __restrict__ dinv,
                            int n, int chunk) {
    __shared__ int tile[SCAN_T];
    int b = blockIdx.x, t = threadIdx.x;
    int beg = b * chunk, end = min(n, beg + chunk);
    int run = boff[b];
    for (int base = beg; base < end; base += SCAN_T) {
        int i = base + t;
        int creal = (i < end) ? cnt[i] : 0;
        int c = (creal + 7) & ~7;
        tile[t] = c;
        __syncthreads();
        for (int off = 1; off < SCAN_T; off <<= 1) {
            int v = (t >= off) ? tile[t - off] : 0;
            __syncthreads();
            tile[t] += v;
            __syncthreads();
        }
        if (i < end) {
            rowptr[i] = run + tile[t] - c; // exclusive prefix of padded counts
            float d = (creal == 0) ? 1.0f : (float)creal;
            dinv[i] = rsqrtf(d);
        }
        run += tile[SCAN_T - 1];
        __syncthreads();
    }
    if (b == gridDim.x - 1 && t == 0) rowptr[n] = run;
}

// atomic-free scatter: pos = rowptr[row] + prank (pad slots stay zero from memset)
__global__ void scatter_k(const int* __restrict__ row, const int* __restrict__ col,
                          const float* __restrict__ ea, const float* __restrict__ dinv,
                          const int* __restrict__ rowptr, const int* __restrict__ prank,
                          int2* __restrict__ cpack, int e) {
    int i = blockIdx.x * blockDim.x + threadIdx.x;
    int stride = gridDim.x * blockDim.x;
    for (; i < e; i += stride) {
        int r = __builtin_nontemporal_load(&row[i]);
        int c = __builtin_nontemporal_load(&col[i]);
        float a = __builtin_nontemporal_load(&ea[i]);
        int pr = __builtin_nontemporal_load(&prank[i]);
        float v = dinv[r] * a * dinv[c];
        int pos = rowptr[r] + pr;
        cpack[pos] = make_int2(c, __float_as_int(v));
    }
}

// out[node][0][:] = x[node][:]  (float4 vectorized)
__global__ void copy_k(const float* __restrict__ x, float* __restrict__ out, int n) {
    int t = blockIdx.x * blockDim.x + threadIdx.x; // n*8 float4s
    if (t < n * 8) {
        int node = t >> 3, q = t & 7;
        ((float4*)out)[(size_t)node * (LSTRIDE / 4) + q] = ((const float4*)x)[t];
    }
}

// one 32-lane group per row; lane = feature; branch-free unroll-8 over padded CSR.
__global__ __launch_bounds__(256) void spmm_k(const int* __restrict__ rowptr,
                                              const unsigned long long* __restrict__ cpack,
                                              const float* __restrict__ pe,
                                              float* __restrict__ out, int n, int layer) {
    int gid = blockIdx.x * 8 + (threadIdx.x >> 5);
    int lane = threadIdx.x & 31;
    if (gid >= n) return;
    float alpha = tanhf(pe[layer]); // BASE_ALPHA = 1
    const float* __restrict__ hsrc = out + (size_t)layer * DF + lane;
    int beg = rowptr[gid], end = rowptr[gid + 1]; // end-beg is a multiple of 8
    float acc = 0.f;
    for (int base = beg; base < end; base += 8) {
        unsigned long long p[8];
#pragma unroll
        for (int u = 0; u < 8; ++u) p[u] = __builtin_nontemporal_load(&cpack[base + u]);
        float h[8];
#pragma unroll
        for (int u = 0; u < 8; ++u)
            h[u] = hsrc[(unsigned)(p[u] & 0xFFFFFFFFu) * (unsigned)LSTRIDE];
#pragma unroll
        for (int u = 0; u < 8; ++u)
            acc = fmaf(__uint_as_float((unsigned)(p[u] >> 32)), h[u], acc);
    }
    out[(size_t)gid * LSTRIDE + (layer + 1) * DF + lane] = alpha * acc;
}

extern "C" void kernel_launch(void* const* d_in, const int* in_sizes, int n_in,
                              void* d_out, int out_size, void* d_ws, size_t ws_size,
                              hipStream_t stream) {
    const float* x  = (const float*)d_in[0];
    const int*   ei = (const int*)d_in[1];
    const float* ea = (const float*)d_in[2];
    const float* pe = (const float*)d_in[3];
    float* out = (float*)d_out;

    const int n = in_sizes[0] / DF;   // 100000
    const int e = in_sizes[2];        // 1600000
    const int* row = ei;
    const int* col = ei + e;

    // workspace layout
    int*   cnt    = (int*)d_ws;               // n
    int*   rowptr = cnt + n;                  // n+1
    float* dinv   = (float*)(rowptr + n + 1); // n
    int*   bsum   = (int*)(dinv + n);         // SCAN_BLOCKS
    int*   boff   = bsum + SCAN_BLOCKS;       // SCAN_BLOCKS
    int*   prank  = boff + SCAN_BLOCKS;       // e
    size_t off = ((size_t)(prank + e) - (size_t)d_ws + 15) & ~(size_t)15;
    int2*  cpack = (int2*)((char*)d_ws + off); // up to e + 7n entries (padded CSR)

    const size_t cpack_entries = (size_t)e + 7ull * (size_t)n;

    hipMemsetAsync(cnt, 0, (size_t)n * sizeof(int), stream);
    hipMemsetAsync(cpack, 0, cpack_entries * sizeof(int2), stream); // pad slots = (0, 0.0f)

    const int chunk = (n + SCAN_BLOCKS - 1) / SCAN_BLOCKS;

    hist_k<<<2048, 256, 0, stream>>>(row, cnt, prank, e);
    scan_partial_k<<<SCAN_BLOCKS, SCAN_T, 0, stream>>>(cnt, bsum, n, chunk);
    scan_bsum_k<<<1, SCAN_BLOCKS, 0, stream>>>(bsum, boff);
    scan_emit_k<<<SCAN_BLOCKS, SCAN_T, 0, stream>>>(cnt, boff, rowptr, dinv, n, chunk);
    scatter_k<<<2048, 256, 0, stream>>>(row, col, ea, dinv, rowptr, prank, cpack, e);
    copy_k<<<(n * 8 + 255) / 256, 256, 0, stream>>>(x, out, n);

    for (int L = 0; L < DEPTH; ++L) {
        spmm_k<<<(n + 7) / 8, 256, 0, stream>>>(rowptr, (const unsigned long long*)cpack,
                                                pe, out, n, L);
    }
}